// Round 12
// baseline (132.673 us; speedup 1.0000x reference)
//
#include <hip/hip_runtime.h>

typedef float  f32x4  __attribute__((ext_vector_type(4)));
typedef float  f32x16 __attribute__((ext_vector_type(16)));
typedef short  s16x8  __attribute__((ext_vector_type(8)));

constexpr int Bn = 4, Sn = 2048, En = 512, Hn = 8;
constexpr int BH = Bn * Hn;   // 32
constexpr int NT2 = Sn / 128; // 16 kv steps of 128 rows (2 x 64-row sub-tiles)
constexpr float QSCL = 0.125f * 1.44269504088896f;  // 1/sqrt(64) * log2(e), folded into q

static __device__ __forceinline__ ushort f2bf(float f) {
  union { float f; uint u; } v; v.f = f;
  uint r = v.u + 0x7fffu + ((v.u >> 16) & 1u);   // RNE
  return (ushort)(r >> 16);
}
static __device__ __forceinline__ uint2 pack4(float a, float b, float c, float d) {
  union { ushort us[4]; uint2 u; } pk;
  pk.us[0] = f2bf(a); pk.us[1] = f2bf(b); pk.us[2] = f2bf(c); pk.us[3] = f2bf(d);
  return pk.u;
}
static __device__ __forceinline__ float hexp2(float x) {
  float r; asm("v_exp_f32 %0, %1" : "=v"(r) : "v"(x)); return r;
}
static __device__ __forceinline__ uint pkbf(float lo, float hi2) {
  uint r; asm("v_cvt_pk_bf16_f32 %0, %1, %2" : "=v"(r) : "v"(lo), "v"(hi2)); return r;
}
#define SWAP32(a, b) asm("v_permlane32_swap_b32 %0, %1" : "+v"(a), "+v"(b))
static __device__ __forceinline__ s16x8 mk8(uint a, uint b, uint c, uint d) {
  union { uint u[4]; s16x8 v; } x; x.u[0] = a; x.u[1] = b; x.u[2] = c; x.u[3] = d; return x.v;
}
#define MFMA32(A, B, C) __builtin_amdgcn_mfma_f32_32x32x16_bf16((A), (B), (C), 0, 0, 0)
#define MFMA16(A, B, C) __builtin_amdgcn_mfma_f32_16x16x32_bf16((A), (B), (C), 0, 0, 0)
#define GLDS(SRC, DST) __builtin_amdgcn_global_load_lds( \
    (const __attribute__((address_space(1))) void*)(SRC), \
    (__attribute__((address_space(3))) void*)(DST), 16, 0, 0)

// ---------------- Kernel 1: per-head projections (MFMA 16x16x32) ----------------
__global__ __launch_bounds__(256) void proj_kernel(
    const float* __restrict__ Qi, const float* __restrict__ Ki, const float* __restrict__ Vi,
    const float* __restrict__ Wq, const float* __restrict__ bq,
    const float* __restrict__ Wk, const float* __restrict__ bk,
    const float* __restrict__ Wv, const float* __restrict__ bv,
    ushort* __restrict__ qo, ushort* __restrict__ ko, ushort* __restrict__ vto)
{
  constexpr int LP = 72;
  __shared__ ushort Xl[64 * LP];
  __shared__ ushort Wl[64 * LP];
  const int role = blockIdx.z;
  const float* X    = role == 0 ? Qi : (role == 1 ? Ki : Vi);
  const float* W    = role == 0 ? Wq : (role == 1 ? Wk : Wv);
  const float* bias = role == 0 ? bq : (role == 1 ? bk : bv);
  const float oscl  = role == 0 ? QSCL : 1.0f;
  const int t = threadIdx.x, lane = t & 63, w = t >> 6;
  const int g = lane >> 4, ql = lane & 15;
  const int bh = blockIdx.y, b = bh >> 3, h = bh & 7;
  const int s0 = blockIdx.x * 64;

  {
    const int row = t >> 4, c = t & 15;
#pragma unroll
    for (int p = 0; p < 4; ++p) {
      const int rr = row + p * 16;
      const float4 wv = *(const float4*)(W + rr * 64 + c * 4);
      *(uint2*)&Wl[rr * LP + c * 4] = pack4(wv.x, wv.y, wv.z, wv.w);
      const float4 xv = *(const float4*)(X + ((size_t)b * Sn + s0 + rr) * En + h * 64 + c * 4);
      *(uint2*)&Xl[rr * LP + c * 4] = pack4(xv.x, xv.y, xv.z, xv.w);
    }
  }
  __syncthreads();

  f32x4 acc[4];
#pragma unroll
  for (int i = 0; i < 4; ++i) acc[i] = (f32x4){0.f, 0.f, 0.f, 0.f};
#pragma unroll
  for (int kc = 0; kc < 2; ++kc) {
    const s16x8 bfrag = *(const s16x8*)&Xl[(w * 16 + ql) * LP + kc * 32 + g * 8];
#pragma unroll
    for (int nt = 0; nt < 4; ++nt) {
      const s16x8 afrag = *(const s16x8*)&Wl[(nt * 16 + ql) * LP + kc * 32 + g * 8];
      acc[nt] = MFMA16(afrag, bfrag, acc[nt]);
    }
  }

  const int s = s0 + w * 16 + ql;
  if (role < 2) {
    ushort* dst = (role == 0 ? qo : ko) + ((size_t)bh * Sn + s) * 64;
#pragma unroll
    for (int nt = 0; nt < 4; ++nt) {
      const int ob = nt * 16 + g * 4;
      *(uint2*)&dst[ob] = pack4((acc[nt][0] + bias[ob]) * oscl, (acc[nt][1] + bias[ob + 1]) * oscl,
                                (acc[nt][2] + bias[ob + 2]) * oscl, (acc[nt][3] + bias[ob + 3]) * oscl);
    }
  } else {
#pragma unroll
    for (int nt = 0; nt < 4; ++nt) {
#pragma unroll
      for (int r = 0; r < 4; ++r) {
        const int o = nt * 16 + g * 4 + r;
        vto[((size_t)bh * 64 + o) * Sn + s] = f2bf(acc[nt][r] + bias[o]);
      }
    }
  }
}

// ---------------- Kernel 2: flash attention, KVBLK=128 as 2 x verified 64-row halves ----------------
// block 512 = 8 waves; wave pair (w, w+4): 32-q col-tile wl=w&3, 32-row k-quarter h2=w>>2
// of each 64-row half. All tile layouts / swizzles / read macros are R6-verbatim on 8KB
// sub-buffers; only the sub-buffer base selects the half. 15 barrier-pairs (vs 31 in R6).
// Step: STAGE T+1 (4 GLDS) -> vmcnt(4) -> barrier -> body(half A) -> body(half B) -> barrier.
__global__ __launch_bounds__(512, 4) void flash_kernel(
    const ushort* __restrict__ q, const ushort* __restrict__ k,
    const ushort* __restrict__ vt, ushort* __restrict__ attn)
{
  __shared__ __align__(16) char smem[65536];      // K0a|K0b|V0a|V0b|K1a|K1b|V1a|V1b (8KB each)
  float* mrg = (float*)smem;
  const int tid = threadIdx.x, lane = tid & 63, w = tid >> 6;
  const int m = lane & 31, hi = lane >> 5;
  const int wl = w & 3, h2 = w >> 2;              // col-tile, k-quarter within each half
  const int hx  = hi ^ (m & 7);                   // K read chunk XOR (R6)
  const int hxv = hx ^ (h2 << 2);                 // V read chunk XOR (R6, k-quarter folded)

  int lid = blockIdx.x + (blockIdx.y << 4);       // 0..511
  lid = (lid & 7) * 64 + (lid >> 3);              // bijective XCD swizzle
  const int bq = lid & 15, bh = lid >> 4;
  const int qrow = bq * 128 + wl * 32 + m;
  const int b = bh >> 3, h = bh & 7;

  // Q fragments (pre-scaled by QSCL in proj)
  const ushort* qp = q + ((size_t)bh * Sn + qrow) * 64 + hi * 8;
  const s16x8 qf0 = *(const s16x8*)(qp + 0);
  const s16x8 qf1 = *(const s16x8*)(qp + 16);
  const s16x8 qf2 = *(const s16x8*)(qp + 32);
  const s16x8 qf3 = *(const s16x8*)(qp + 48);

  // staging (R6 pattern): 512 threads, row tid>>3, 16B chunk (tid&7)^(row&7)
  const int srow = tid >> 3, sc = tid & 7, scs = sc ^ (srow & 7);
  const ushort* kS = k  + (size_t)bh * Sn * 64 + (size_t)srow * 64 + scs * 8;
  const ushort* vS = vt + ((size_t)bh * 64 + srow) * Sn + scs * 8;
  const uint dO = (uint)(tid * 16);
  char* K0a = smem;          char* K0b = smem + 8192;
  char* V0a = smem + 16384;  char* V0b = smem + 24576;
  char* K1a = smem + 32768;  char* K1b = smem + 40960;
  char* V1a = smem + 49152;  char* V1b = smem + 57344;

  const f32x16 z16 = {};
  f32x16 acc0 = {}, acc1 = {}, asum = {};
  union { ushort us[8]; s16x8 v; } onesU;
#pragma unroll
  for (int i = 0; i < 8; ++i) onesU.us[i] = 0x3F80;   // bf16 1.0
  const s16x8 ones = onesU.v;

  // stage one 128-row tile: K rows +0..63 -> KA, +64..127 -> KB; V k +0..63 -> VA, +64..127 -> VB
#define STAGE(KA, KBB, VA, VBB) do {                                        \
    GLDS(kS, (KA) + dO);  GLDS(kS + 4096, (KBB) + dO);                      \
    GLDS(vS, (VA) + dO);  GLDS(vS + 64,   (VBB) + dO);                      \
    kS += 8192; vS += 128;                                                  \
  } while (0)

  // prologue: stage tile 0 -> buf 0
  STAGE(K0a, K0b, V0a, V0b);

  // R6-verbatim read macros (8KB sub-buffer base passed in)
#define LDK(KB, S)     (*(const s16x8*)((KB) + ((h2 * 32 + m) * 64 + (((2 * (S)) ^ hx ) << 3)) * 2))
#define LDV(VB, DT, S) (*(const s16x8*)((VB) + (((DT) * 32 + m) * 64 + (((2 * (S)) ^ hxv) << 3)) * 2))

  // R6-verbatim 64-row body on one (K,V) sub-tile pair
#define HALF(KB, VB) do {                                                   \
    f32x16 sta, stb;                                                        \
    __builtin_amdgcn_s_setprio(1);                                          \
    sta = MFMA32(LDK(KB, 0), qf0, z16);                                     \
    sta = MFMA32(LDK(KB, 1), qf1, sta);                                     \
    stb = MFMA32(LDK(KB, 2), qf2, z16);                                     \
    stb = MFMA32(LDK(KB, 3), qf3, stb);                                     \
    __builtin_amdgcn_s_setprio(0);                                          \
    f32x16 p;                                                               \
    _Pragma("unroll")                                                       \
    for (int i = 0; i < 16; ++i) p[i] = hexp2(sta[i] + stb[i]);             \
    uint uA, uB, uC, uD, uE, uF, uG, uH;                                    \
    uA = pkbf(p[0], p[1]);   uB = pkbf(p[4], p[5]);   SWAP32(uA, uB);       \
    uC = pkbf(p[2], p[3]);   uD = pkbf(p[6], p[7]);   SWAP32(uC, uD);       \
    uE = pkbf(p[8], p[9]);   uF = pkbf(p[12], p[13]); SWAP32(uE, uF);       \
    uG = pkbf(p[10], p[11]); uH = pkbf(p[14], p[15]); SWAP32(uG, uH);       \
    const s16x8 pb0 = mk8(uA, uC, uB, uD);                                  \
    const s16x8 pb1 = mk8(uE, uG, uF, uH);                                  \
    __builtin_amdgcn_s_setprio(1);                                          \
    acc0 = MFMA32(LDV(VB, 0, 0), pb0, acc0);                                \
    acc0 = MFMA32(LDV(VB, 0, 1), pb1, acc0);                                \
    acc1 = MFMA32(LDV(VB, 1, 0), pb0, acc1);                                \
    acc1 = MFMA32(LDV(VB, 1, 1), pb1, acc1);                                \
    asum = MFMA32(ones, pb0, asum);                                         \
    asum = MFMA32(ones, pb1, asum);                                         \
    __builtin_amdgcn_s_setprio(0);                                          \
  } while (0)

#define STEP(T, KA, KBB, VA, VBB, NKA, NKB, NVA, NVB) do {                  \
    if ((T) < NT2 - 1) {                                                    \
      STAGE(NKA, NKB, NVA, NVB);                                            \
      asm volatile("s_waitcnt vmcnt(4)" ::: "memory");                      \
    } else {                                                                \
      asm volatile("s_waitcnt vmcnt(0)" ::: "memory");                      \
    }                                                                       \
    __builtin_amdgcn_s_barrier();                                           \
    __builtin_amdgcn_sched_barrier(0);                                      \
    HALF(KA, VA);                                                           \
    HALF(KBB, VBB);                                                         \
    __builtin_amdgcn_s_barrier();                                           \
    __builtin_amdgcn_sched_barrier(0);                                      \
  } while (0)

  for (int T = 0; T < NT2; T += 2) {
    STEP(T,     K0a, K0b, V0a, V0b, K1a, K1b, V1a, V1b);
    STEP(T + 1, K1a, K1b, V1a, V1b, K0a, K0b, V0a, V0b);
  }
#undef STEP
#undef HALF
#undef LDK
#undef LDV
#undef STAGE

  // ---- epilogue: merge k-quarter partials (pair w <-> w+4) with plain adds ----
  const float lT = asum[0];                           // row-sum over this wave's k set
  float* mp = mrg + (size_t)(wl * 64 + lane) * 36;    // 144B stride, 16B aligned
  __syncthreads();                                    // drain LDS reads before overwrite
  if (h2) {
#pragma unroll
    for (int i = 0; i < 4; ++i) {
      f32x4 t0 = {acc0[4 * i], acc0[4 * i + 1], acc0[4 * i + 2], acc0[4 * i + 3]};
      f32x4 t1 = {acc1[4 * i], acc1[4 * i + 1], acc1[4 * i + 2], acc1[4 * i + 3]};
      *(f32x4*)(mp + 4 * i) = t0;
      *(f32x4*)(mp + 16 + 4 * i) = t1;
    }
    mp[32] = lT;
  }
  __syncthreads();
  if (!h2) {
    const float inv = 1.0f / (lT + mp[32]);
    ushort* ap = attn + ((size_t)(b * Sn + qrow)) * En + h * 64;
#pragma unroll
    for (int g2 = 0; g2 < 4; ++g2) {
      float a0 = (acc0[g2 * 4 + 0] + mp[g2 * 4 + 0]) * inv;
      float a1 = (acc0[g2 * 4 + 1] + mp[g2 * 4 + 1]) * inv;
      float a2 = (acc0[g2 * 4 + 2] + mp[g2 * 4 + 2]) * inv;
      float a3 = (acc0[g2 * 4 + 3] + mp[g2 * 4 + 3]) * inv;
      float c0 = (acc1[g2 * 4 + 0] + mp[16 + g2 * 4 + 0]) * inv;
      float c1 = (acc1[g2 * 4 + 1] + mp[16 + g2 * 4 + 1]) * inv;
      float c2 = (acc1[g2 * 4 + 2] + mp[16 + g2 * 4 + 2]) * inv;
      float c3 = (acc1[g2 * 4 + 3] + mp[16 + g2 * 4 + 3]) * inv;
      uint2 u0, u1;
      u0.x = pkbf(a0, a1); u0.y = pkbf(a2, a3);
      u1.x = pkbf(c0, c1); u1.y = pkbf(c2, c3);
      *(uint2*)&ap[g2 * 8 + hi * 4]      = u0;   // d = g2*8 + 4*hi + 0..3
      *(uint2*)&ap[32 + g2 * 8 + hi * 4] = u1;   // d = 32 + ...
    }
  }
}

// ---------------- Kernel 3: output projection, 128x128 tile, 8 waves (R9 verbatim) ----------------
__global__ __launch_bounds__(512) void outproj_kernel(
    const ushort* __restrict__ attn, const float* __restrict__ Wo,
    const float* __restrict__ bo, float* __restrict__ out)
{
  constexpr int LP = 72;
  __shared__ ushort Al[128 * LP];   // attn tile [m 128][e 64]
  __shared__ ushort Wl[128 * LP];   // Wo tile [n 128][e 64]
  const int t = threadIdx.x, lane = t & 63, w = t >> 6;
  const int g = lane >> 4, ml = lane & 15;
  const int wm = w >> 2, wn = w & 3;
  const int m0 = blockIdx.x * 128, n0 = blockIdx.y * 128;
  f32x4 acc[4][2];
#pragma unroll
  for (int i = 0; i < 4; ++i)
#pragma unroll
    for (int j = 0; j < 2; ++j) acc[i][j] = (f32x4){0.f, 0.f, 0.f, 0.f};

  const int srow = t >> 2, c0 = t & 3;     // 4 threads per row
  for (int e0 = 0; e0 < En; e0 += 64) {
    __syncthreads();
#pragma unroll
    for (int p = 0; p < 2; ++p) {          // attn: 8 chunks of 8 bf16 per row
      const int c = c0 + p * 4;
      const uint4 v = *(const uint4*)(attn + ((size_t)(m0 + srow)) * En + e0 + c * 8);
      *(uint4*)&Al[srow * LP + c * 8] = v;
    }
#pragma unroll
    for (int p = 0; p < 4; ++p) {          // Wo: 16 float4 per row, convert to bf16
      const int c = c0 + p * 4;
      const float4 v = *(const float4*)(Wo + ((size_t)(n0 + srow)) * En + e0 + c * 4);
      *(uint2*)&Wl[srow * LP + c * 4] = pack4(v.x, v.y, v.z, v.w);
    }
    __syncthreads();
#pragma unroll
    for (int kc = 0; kc < 2; ++kc) {
      s16x8 bfr[4];
#pragma unroll
      for (int mf = 0; mf < 4; ++mf)
        bfr[mf] = *(const s16x8*)&Al[(wm * 64 + mf * 16 + ml) * LP + kc * 32 + g * 8];
#pragma unroll
      for (int nf = 0; nf < 2; ++nf) {
        const s16x8 afr = *(const s16x8*)&Wl[(wn * 32 + nf * 16 + ml) * LP + kc * 32 + g * 8];
#pragma unroll
        for (int mf = 0; mf < 4; ++mf)
          acc[mf][nf] = MFMA16(afr, bfr[mf], acc[mf][nf]);
      }
    }
  }
#pragma unroll
  for (int mf = 0; mf < 4; ++mf) {
    const int mrow = m0 + wm * 64 + mf * 16 + ml;
#pragma unroll
    for (int nf = 0; nf < 2; ++nf) {
      const int ncol = n0 + wn * 32 + nf * 16 + g * 4;
      const float4 bias = *(const float4*)(bo + ncol);
      float4 o;
      o.x = acc[mf][nf][0] + bias.x;
      o.y = acc[mf][nf][1] + bias.y;
      o.z = acc[mf][nf][2] + bias.z;
      o.w = acc[mf][nf][3] + bias.w;
      *(float4*)&out[(size_t)mrow * En + ncol] = o;
    }
  }
}

extern "C" void kernel_launch(void* const* d_in, const int* in_sizes, int n_in,
                              void* d_out, int out_size, void* d_ws, size_t ws_size,
                              hipStream_t stream) {
  const float* Qi = (const float*)d_in[0];
  const float* Ki = (const float*)d_in[1];
  const float* Vi = (const float*)d_in[2];
  const float* Wq = (const float*)d_in[3];
  const float* bq = (const float*)d_in[4];
  const float* Wk = (const float*)d_in[5];
  const float* bk = (const float*)d_in[6];
  const float* Wv = (const float*)d_in[7];
  const float* bv = (const float*)d_in[8];
  const float* Wo = (const float*)d_in[9];
  const float* bo = (const float*)d_in[10];

  const size_t TEN = (size_t)BH * Sn * 64;   // 4 Mi elems per bf16 tensor
  ushort* qw  = (ushort*)d_ws;
  ushort* kw  = qw + TEN;
  ushort* vtw = kw + TEN;
  ushort* at  = vtw + TEN;                   // total 32 MB of ws

  proj_kernel<<<dim3(Sn / 64, BH, 3), 256, 0, stream>>>(
      Qi, Ki, Vi, Wq, bq, Wk, bk, Wv, bv, qw, kw, vtw);
  flash_kernel<<<dim3(16, 32), 512, 0, stream>>>(qw, kw, vtw, at);
  outproj_kernel<<<dim3(Bn * Sn / 128, En / 128), 512, 0, stream>>>(
      at, Wo, bo, (float*)d_out);
}

// Round 13
// 81.258 us; speedup vs baseline: 1.6327x; 1.6327x over previous
//
#include <hip/hip_runtime.h>

typedef float  f32x4  __attribute__((ext_vector_type(4)));
typedef float  f32x16 __attribute__((ext_vector_type(16)));
typedef short  s16x8  __attribute__((ext_vector_type(8)));

constexpr int Bn = 4, Sn = 2048, En = 512, Hn = 8;
constexpr int BH = Bn * Hn;   // 32
constexpr int NT = Sn / 64;   // 32 kv tiles
constexpr float QSCL = 0.125f * 1.44269504088896f;  // 1/sqrt(64) * log2(e), folded into q

static __device__ __forceinline__ ushort f2bf(float f) {
  union { float f; uint u; } v; v.f = f;
  uint r = v.u + 0x7fffu + ((v.u >> 16) & 1u);   // RNE
  return (ushort)(r >> 16);
}
static __device__ __forceinline__ float hexp2(float x) {
  float r; asm("v_exp_f32 %0, %1" : "=v"(r) : "v"(x)); return r;
}
static __device__ __forceinline__ uint pkbf(float lo, float hi2) {
  uint r; asm("v_cvt_pk_bf16_f32 %0, %1, %2" : "=v"(r) : "v"(lo), "v"(hi2)); return r;
}
static __device__ __forceinline__ uint2 pack4(float a, float b, float c, float d) {
  uint2 u; u.x = pkbf(a, b); u.y = pkbf(c, d); return u;   // 2 insts, RNE
}
#define SWAP32(a, b) asm("v_permlane32_swap_b32 %0, %1" : "+v"(a), "+v"(b))
static __device__ __forceinline__ s16x8 mk8(uint a, uint b, uint c, uint d) {
  union { uint u[4]; s16x8 v; } x; x.u[0] = a; x.u[1] = b; x.u[2] = c; x.u[3] = d; return x.v;
}
#define MFMA32(A, B, C) __builtin_amdgcn_mfma_f32_32x32x16_bf16((A), (B), (C), 0, 0, 0)
#define MFMA16(A, B, C) __builtin_amdgcn_mfma_f32_16x16x32_bf16((A), (B), (C), 0, 0, 0)
#define GLDS(SRC, DST) __builtin_amdgcn_global_load_lds( \
    (const __attribute__((address_space(1))) void*)(SRC), \
    (__attribute__((address_space(3))) void*)(DST), 16, 0, 0)

// ---------------- Kernel 1: per-head projections (MFMA 16x16x32) ----------------
// role 0=q (pre-scaled), 1=k -> [BH,S,64]; role 2=v -> [BH,64,S] via LDS transpose
// (coalesced 16B stores instead of scattered 2B).
__global__ __launch_bounds__(256) void proj_kernel(
    const float* __restrict__ Qi, const float* __restrict__ Ki, const float* __restrict__ Vi,
    const float* __restrict__ Wq, const float* __restrict__ bq,
    const float* __restrict__ Wk, const float* __restrict__ bk,
    const float* __restrict__ Wv, const float* __restrict__ bv,
    ushort* __restrict__ qo, ushort* __restrict__ ko, ushort* __restrict__ vto)
{
  constexpr int LP = 72;
  __shared__ ushort Xl[64 * LP];
  __shared__ ushort Wl[64 * LP];
  const int role = blockIdx.z;
  const float* X    = role == 0 ? Qi : (role == 1 ? Ki : Vi);
  const float* W    = role == 0 ? Wq : (role == 1 ? Wk : Wv);
  const float* bias = role == 0 ? bq : (role == 1 ? bk : bv);
  const float oscl  = role == 0 ? QSCL : 1.0f;
  const int t = threadIdx.x, lane = t & 63, w = t >> 6;
  const int g = lane >> 4, ql = lane & 15;
  const int bh = blockIdx.y, b = bh >> 3, h = bh & 7;
  const int s0 = blockIdx.x * 64;

  {
    const int row = t >> 4, c = t & 15;
#pragma unroll
    for (int p = 0; p < 4; ++p) {
      const int rr = row + p * 16;
      const float4 wv = *(const float4*)(W + rr * 64 + c * 4);
      *(uint2*)&Wl[rr * LP + c * 4] = pack4(wv.x, wv.y, wv.z, wv.w);
      const float4 xv = *(const float4*)(X + ((size_t)b * Sn + s0 + rr) * En + h * 64 + c * 4);
      *(uint2*)&Xl[rr * LP + c * 4] = pack4(xv.x, xv.y, xv.z, xv.w);
    }
  }
  __syncthreads();

  f32x4 acc[4];
#pragma unroll
  for (int i = 0; i < 4; ++i) acc[i] = (f32x4){0.f, 0.f, 0.f, 0.f};
#pragma unroll
  for (int kc = 0; kc < 2; ++kc) {
    const s16x8 bfrag = *(const s16x8*)&Xl[(w * 16 + ql) * LP + kc * 32 + g * 8];
#pragma unroll
    for (int nt = 0; nt < 4; ++nt) {
      const s16x8 afrag = *(const s16x8*)&Wl[(nt * 16 + ql) * LP + kc * 32 + g * 8];
      acc[nt] = MFMA16(afrag, bfrag, acc[nt]);
    }
  }

  const int s = s0 + w * 16 + ql;
  if (role < 2) {
    ushort* dst = (role == 0 ? qo : ko) + ((size_t)bh * Sn + s) * 64;
#pragma unroll
    for (int nt = 0; nt < 4; ++nt) {
      const int ob = nt * 16 + g * 4;
      *(uint2*)&dst[ob] = pack4((acc[nt][0] + bias[ob]) * oscl, (acc[nt][1] + bias[ob + 1]) * oscl,
                                (acc[nt][2] + bias[ob + 2]) * oscl, (acc[nt][3] + bias[ob + 3]) * oscl);
    }
  } else {
    // transpose via LDS (reuse Xl after all MFMA reads complete)
    __syncthreads();
#pragma unroll
    for (int nt = 0; nt < 4; ++nt)
#pragma unroll
      for (int r = 0; r < 4; ++r) {
        const int o = nt * 16 + g * 4 + r;
        Xl[o * LP + w * 16 + ql] = f2bf(acc[nt][r] + bias[o]);
      }
    __syncthreads();
    const int ro = t >> 3, ch = t & 7;     // 32 o-rows per pass, 8x 16B chunks
#pragma unroll
    for (int p = 0; p < 2; ++p) {
      const int row = ro + p * 32;
      const uint4 v = *(const uint4*)&Xl[row * LP + ch * 8];
      *(uint4*)&vto[((size_t)bh * 64 + row) * Sn + s0 + ch * 8] = v;
    }
  }
}

// ---------------- Kernel 2: flash attention (R6/R11 verbatim — banked best, 49.4 us) ----------------
// block 512 = 8 waves; wave pair (w, w+4): 32-q col-tile wl=w&3, k-half h2=w>>2;
// max-free softmax; counted vmcnt(2); 2 barriers/step; ones-MFMA row-sum; LDS merge.
__global__ __launch_bounds__(512, 4) void flash_kernel(
    const ushort* __restrict__ q, const ushort* __restrict__ k,
    const ushort* __restrict__ vt, ushort* __restrict__ attn)
{
  __shared__ __align__(16) char smem[36864];      // K0|K1|V0|V1 (8KB each) / merge area
  float* mrg = (float*)smem;
  const int tid = threadIdx.x, lane = tid & 63, w = tid >> 6;
  const int m = lane & 31, hi = lane >> 5;
  const int wl = w & 3, h2 = w >> 2;              // col-tile, k-half
  const int hx  = hi ^ (m & 7);                   // K read chunk XOR
  const int hxv = hx ^ (h2 << 2);                 // V read chunk XOR (k-half folded)

  int lid = blockIdx.x + (blockIdx.y << 4);       // 0..511
  lid = (lid & 7) * 64 + (lid >> 3);              // bijective XCD swizzle
  const int bq = lid & 15, bh = lid >> 4;
  const int qrow = bq * 128 + wl * 32 + m;
  const int b = bh >> 3, h = bh & 7;

  const ushort* qp = q + ((size_t)bh * Sn + qrow) * 64 + hi * 8;
  const s16x8 qf0 = *(const s16x8*)(qp + 0);
  const s16x8 qf1 = *(const s16x8*)(qp + 16);
  const s16x8 qf2 = *(const s16x8*)(qp + 32);
  const s16x8 qf3 = *(const s16x8*)(qp + 48);

  const int srow = tid >> 3, sc = tid & 7, scs = sc ^ (srow & 7);
  const ushort* kS = k  + (size_t)bh * Sn * 64 + (size_t)srow * 64 + scs * 8;
  const ushort* vS = vt + ((size_t)bh * 64 + srow) * Sn + scs * 8;
  const uint dO = (uint)(tid * 16);
  char* KB0 = smem;          char* KB1 = smem + 8192;
  char* VB0 = smem + 16384;  char* VB1 = smem + 24576;

  const f32x16 z16 = {};
  f32x16 acc0 = {}, acc1 = {}, asum = {};
  union { ushort us[8]; s16x8 v; } onesU;
#pragma unroll
  for (int i = 0; i < 8; ++i) onesU.us[i] = 0x3F80;   // bf16 1.0
  const s16x8 ones = onesU.v;

  GLDS(kS, KB0 + dO); GLDS(vS, VB0 + dO);
  kS += 4096; vS += 64;

#define LDK(KB, S)     (*(const s16x8*)((KB)  + ((h2 * 32 + m) * 64 + (((2 * (S)) ^ hx ) << 3)) * 2))
#define LDV(VB, DT, S) (*(const s16x8*)((VB)  + (((DT) * 32 + m) * 64 + (((2 * (S)) ^ hxv) << 3)) * 2))

#define STEP(T, KB, VB, KBn, VBn) do {                                      \
    if ((T) < NT - 1) {                                                     \
      GLDS(kS, (KBn) + dO); GLDS(vS, (VBn) + dO);                           \
      kS += 4096; vS += 64;                                                 \
      asm volatile("s_waitcnt vmcnt(2)" ::: "memory");                      \
    } else {                                                                \
      asm volatile("s_waitcnt vmcnt(0)" ::: "memory");                      \
    }                                                                       \
    __builtin_amdgcn_s_barrier();                                           \
    __builtin_amdgcn_sched_barrier(0);                                      \
    f32x16 sta, stb;                                                        \
    __builtin_amdgcn_s_setprio(1);                                          \
    sta = MFMA32(LDK(KB, 0), qf0, z16);                                     \
    sta = MFMA32(LDK(KB, 1), qf1, sta);                                     \
    stb = MFMA32(LDK(KB, 2), qf2, z16);                                     \
    stb = MFMA32(LDK(KB, 3), qf3, stb);                                     \
    __builtin_amdgcn_s_setprio(0);                                          \
    f32x16 p;                                                               \
    _Pragma("unroll")                                                       \
    for (int i = 0; i < 16; ++i) p[i] = hexp2(sta[i] + stb[i]);             \
    uint uA, uB, uC, uD, uE, uF, uG, uH;                                    \
    uA = pkbf(p[0], p[1]);   uB = pkbf(p[4], p[5]);   SWAP32(uA, uB);       \
    uC = pkbf(p[2], p[3]);   uD = pkbf(p[6], p[7]);   SWAP32(uC, uD);       \
    uE = pkbf(p[8], p[9]);   uF = pkbf(p[12], p[13]); SWAP32(uE, uF);       \
    uG = pkbf(p[10], p[11]); uH = pkbf(p[14], p[15]); SWAP32(uG, uH);       \
    const s16x8 pb0 = mk8(uA, uC, uB, uD);                                  \
    const s16x8 pb1 = mk8(uE, uG, uF, uH);                                  \
    __builtin_amdgcn_s_setprio(1);                                          \
    acc0 = MFMA32(LDV(VB, 0, 0), pb0, acc0);                                \
    acc0 = MFMA32(LDV(VB, 0, 1), pb1, acc0);                                \
    acc1 = MFMA32(LDV(VB, 1, 0), pb0, acc1);                                \
    acc1 = MFMA32(LDV(VB, 1, 1), pb1, acc1);                                \
    asum = MFMA32(ones, pb0, asum);                                         \
    asum = MFMA32(ones, pb1, asum);                                         \
    __builtin_amdgcn_s_setprio(0);                                          \
    __builtin_amdgcn_s_barrier();                                           \
    __builtin_amdgcn_sched_barrier(0);                                      \
  } while (0)

  for (int T = 0; T < NT; T += 2) {
    STEP(T,     KB0, VB0, KB1, VB1);
    STEP(T + 1, KB1, VB1, KB0, VB0);
  }
#undef STEP
#undef LDK
#undef LDV

  const float lT = asum[0];                           // row-sum over this k-half
  float* mp = mrg + (size_t)(wl * 64 + lane) * 36;    // 144B stride, 16B aligned
  __syncthreads();                                    // drain LDS reads before overwrite
  if (h2) {
#pragma unroll
    for (int i = 0; i < 4; ++i) {
      f32x4 t0 = {acc0[4 * i], acc0[4 * i + 1], acc0[4 * i + 2], acc0[4 * i + 3]};
      f32x4 t1 = {acc1[4 * i], acc1[4 * i + 1], acc1[4 * i + 2], acc1[4 * i + 3]};
      *(f32x4*)(mp + 4 * i) = t0;
      *(f32x4*)(mp + 16 + 4 * i) = t1;
    }
    mp[32] = lT;
  }
  __syncthreads();
  if (!h2) {
    const float inv = 1.0f / (lT + mp[32]);
    ushort* ap = attn + ((size_t)(b * Sn + qrow)) * En + h * 64;
#pragma unroll
    for (int g2 = 0; g2 < 4; ++g2) {
      float a0 = (acc0[g2 * 4 + 0] + mp[g2 * 4 + 0]) * inv;
      float a1 = (acc0[g2 * 4 + 1] + mp[g2 * 4 + 1]) * inv;
      float a2 = (acc0[g2 * 4 + 2] + mp[g2 * 4 + 2]) * inv;
      float a3 = (acc0[g2 * 4 + 3] + mp[g2 * 4 + 3]) * inv;
      float c0 = (acc1[g2 * 4 + 0] + mp[16 + g2 * 4 + 0]) * inv;
      float c1 = (acc1[g2 * 4 + 1] + mp[16 + g2 * 4 + 1]) * inv;
      float c2 = (acc1[g2 * 4 + 2] + mp[16 + g2 * 4 + 2]) * inv;
      float c3 = (acc1[g2 * 4 + 3] + mp[16 + g2 * 4 + 3]) * inv;
      uint2 u0, u1;
      u0.x = pkbf(a0, a1); u0.y = pkbf(a2, a3);
      u1.x = pkbf(c0, c1); u1.y = pkbf(c2, c3);
      *(uint2*)&ap[g2 * 8 + hi * 4]      = u0;   // d = g2*8 + 4*hi + 0..3
      *(uint2*)&ap[32 + g2 * 8 + hi * 4] = u1;   // d = 32 + ...
    }
  }
}

// ---------------- Kernel 3: output projection, 128x128 tile, 8 waves (R9 verbatim) ----------------
__global__ __launch_bounds__(512) void outproj_kernel(
    const ushort* __restrict__ attn, const float* __restrict__ Wo,
    const float* __restrict__ bo, float* __restrict__ out)
{
  constexpr int LP = 72;
  __shared__ ushort Al[128 * LP];   // attn tile [m 128][e 64]
  __shared__ ushort Wl[128 * LP];   // Wo tile [n 128][e 64]
  const int t = threadIdx.x, lane = t & 63, w = t >> 6;
  const int g = lane >> 4, ml = lane & 15;
  const int wm = w >> 2, wn = w & 3;
  const int m0 = blockIdx.x * 128, n0 = blockIdx.y * 128;
  f32x4 acc[4][2];
#pragma unroll
  for (int i = 0; i < 4; ++i)
#pragma unroll
    for (int j = 0; j < 2; ++j) acc[i][j] = (f32x4){0.f, 0.f, 0.f, 0.f};

  const int srow = t >> 2, c0 = t & 3;     // 4 threads per row
  for (int e0 = 0; e0 < En; e0 += 64) {
    __syncthreads();
#pragma unroll
    for (int p = 0; p < 2; ++p) {          // attn: 8 chunks of 8 bf16 per row
      const int c = c0 + p * 4;
      const uint4 v = *(const uint4*)(attn + ((size_t)(m0 + srow)) * En + e0 + c * 8);
      *(uint4*)&Al[srow * LP + c * 8] = v;
    }
#pragma unroll
    for (int p = 0; p < 4; ++p) {          // Wo: 16 float4 per row, convert to bf16
      const int c = c0 + p * 4;
      const float4 v = *(const float4*)(Wo + ((size_t)(n0 + srow)) * En + e0 + c * 4);
      *(uint2*)&Wl[srow * LP + c * 4] = pack4(v.x, v.y, v.z, v.w);
    }
    __syncthreads();
#pragma unroll
    for (int kc = 0; kc < 2; ++kc) {
      s16x8 bfr[4];
#pragma unroll
      for (int mf = 0; mf < 4; ++mf)
        bfr[mf] = *(const s16x8*)&Al[(wm * 64 + mf * 16 + ml) * LP + kc * 32 + g * 8];
#pragma unroll
      for (int nf = 0; nf < 2; ++nf) {
        const s16x8 afr = *(const s16x8*)&Wl[(wn * 32 + nf * 16 + ml) * LP + kc * 32 + g * 8];
#pragma unroll
        for (int mf = 0; mf < 4; ++mf)
          acc[mf][nf] = MFMA16(afr, bfr[mf], acc[mf][nf]);
      }
    }
  }
#pragma unroll
  for (int mf = 0; mf < 4; ++mf) {
    const int mrow = m0 + wm * 64 + mf * 16 + ml;
#pragma unroll
    for (int nf = 0; nf < 2; ++nf) {
      const int ncol = n0 + wn * 32 + nf * 16 + g * 4;
      const float4 bias = *(const float4*)(bo + ncol);
      float4 o;
      o.x = acc[mf][nf][0] + bias.x;
      o.y = acc[mf][nf][1] + bias.y;
      o.z = acc[mf][nf][2] + bias.z;
      o.w = acc[mf][nf][3] + bias.w;
      *(float4*)&out[(size_t)mrow * En + ncol] = o;
    }
  }
}

extern "C" void kernel_launch(void* const* d_in, const int* in_sizes, int n_in,
                              void* d_out, int out_size, void* d_ws, size_t ws_size,
                              hipStream_t stream) {
  const float* Qi = (const float*)d_in[0];
  const float* Ki = (const float*)d_in[1];
  const float* Vi = (const float*)d_in[2];
  const float* Wq = (const float*)d_in[3];
  const float* bq = (const float*)d_in[4];
  const float* Wk = (const float*)d_in[5];
  const float* bk = (const float*)d_in[6];
  const float* Wv = (const float*)d_in[7];
  const float* bv = (const float*)d_in[8];
  const float* Wo = (const float*)d_in[9];
  const float* bo = (const float*)d_in[10];

  const size_t TEN = (size_t)BH * Sn * 64;   // 4 Mi elems per bf16 tensor
  ushort* qw  = (ushort*)d_ws;
  ushort* kw  = qw + TEN;
  ushort* vtw = kw + TEN;
  ushort* at  = vtw + TEN;                   // total 32 MB of ws

  proj_kernel<<<dim3(Sn / 64, BH, 3), 256, 0, stream>>>(
      Qi, Ki, Vi, Wq, bq, Wk, bk, Wv, bv, qw, kw, vtw);
  flash_kernel<<<dim3(16, 32), 512, 0, stream>>>(qw, kw, vtw, at);
  outproj_kernel<<<dim3(Bn * Sn / 128, En / 128), 512, 0, stream>>>(
      at, Wo, bo, (float*)d_out);
}

// Round 14
// 77.700 us; speedup vs baseline: 1.7075x; 1.0458x over previous
//
#include <hip/hip_runtime.h>

typedef float  f32x4  __attribute__((ext_vector_type(4)));
typedef float  f32x16 __attribute__((ext_vector_type(16)));
typedef short  s16x8  __attribute__((ext_vector_type(8)));

constexpr int Bn = 4, Sn = 2048, En = 512, Hn = 8;
constexpr int BH = Bn * Hn;   // 32
constexpr int NT = Sn / 64;   // 32 kv tiles
constexpr float QSCL = 0.125f * 1.44269504088896f;  // 1/sqrt(64) * log2(e), folded into q

static __device__ __forceinline__ ushort f2bf(float f) {
  union { float f; uint u; } v; v.f = f;
  uint r = v.u + 0x7fffu + ((v.u >> 16) & 1u);   // RNE
  return (ushort)(r >> 16);
}
static __device__ __forceinline__ float hexp2(float x) {
  float r; asm("v_exp_f32 %0, %1" : "=v"(r) : "v"(x)); return r;
}
static __device__ __forceinline__ uint pkbf(float lo, float hi2) {
  uint r; asm("v_cvt_pk_bf16_f32 %0, %1, %2" : "=v"(r) : "v"(lo), "v"(hi2)); return r;
}
static __device__ __forceinline__ uint2 pack4(float a, float b, float c, float d) {
  uint2 u; u.x = pkbf(a, b); u.y = pkbf(c, d); return u;   // 2 insts, RNE
}
#define SWAP32(a, b) asm("v_permlane32_swap_b32 %0, %1" : "+v"(a), "+v"(b))
static __device__ __forceinline__ s16x8 mk8(uint a, uint b, uint c, uint d) {
  union { uint u[4]; s16x8 v; } x; x.u[0] = a; x.u[1] = b; x.u[2] = c; x.u[3] = d; return x.v;
}
#define MFMA32(A, B, C) __builtin_amdgcn_mfma_f32_32x32x16_bf16((A), (B), (C), 0, 0, 0)
#define MFMA16(A, B, C) __builtin_amdgcn_mfma_f32_16x16x32_bf16((A), (B), (C), 0, 0, 0)
#define GLDS(SRC, DST) __builtin_amdgcn_global_load_lds( \
    (const __attribute__((address_space(1))) void*)(SRC), \
    (__attribute__((address_space(3))) void*)(DST), 16, 0, 0)

// ---------------- Kernel 1: per-head projections (MFMA 16x16x32) ----------------
// role 0=q (pre-scaled), 1=k -> [BH,S,64]; role 2=v -> [BH,64,S].
// ALL outputs routed through LDS so global stores are coalesced 16B chunks
// (q/k: row-major [s][o] rows of 128B; v: transposed [o][s] rows).
__global__ __launch_bounds__(256) void proj_kernel(
    const float* __restrict__ Qi, const float* __restrict__ Ki, const float* __restrict__ Vi,
    const float* __restrict__ Wq, const float* __restrict__ bq,
    const float* __restrict__ Wk, const float* __restrict__ bk,
    const float* __restrict__ Wv, const float* __restrict__ bv,
    ushort* __restrict__ qo, ushort* __restrict__ ko, ushort* __restrict__ vto)
{
  constexpr int LP = 72;
  __shared__ ushort Xl[64 * LP];
  __shared__ ushort Wl[64 * LP];
  const int role = blockIdx.z;
  const float* X    = role == 0 ? Qi : (role == 1 ? Ki : Vi);
  const float* W    = role == 0 ? Wq : (role == 1 ? Wk : Wv);
  const float* bias = role == 0 ? bq : (role == 1 ? bk : bv);
  const float oscl  = role == 0 ? QSCL : 1.0f;
  const int t = threadIdx.x, lane = t & 63, w = t >> 6;
  const int g = lane >> 4, ql = lane & 15;
  const int bh = blockIdx.y, b = bh >> 3, h = bh & 7;
  const int s0 = blockIdx.x * 64;

  {
    const int row = t >> 4, c = t & 15;
#pragma unroll
    for (int p = 0; p < 4; ++p) {
      const int rr = row + p * 16;
      const float4 wv = *(const float4*)(W + rr * 64 + c * 4);
      *(uint2*)&Wl[rr * LP + c * 4] = pack4(wv.x, wv.y, wv.z, wv.w);
      const float4 xv = *(const float4*)(X + ((size_t)b * Sn + s0 + rr) * En + h * 64 + c * 4);
      *(uint2*)&Xl[rr * LP + c * 4] = pack4(xv.x, xv.y, xv.z, xv.w);
    }
  }
  __syncthreads();

  f32x4 acc[4];
#pragma unroll
  for (int i = 0; i < 4; ++i) acc[i] = (f32x4){0.f, 0.f, 0.f, 0.f};
#pragma unroll
  for (int kc = 0; kc < 2; ++kc) {
    const s16x8 bfrag = *(const s16x8*)&Xl[(w * 16 + ql) * LP + kc * 32 + g * 8];
#pragma unroll
    for (int nt = 0; nt < 4; ++nt) {
      const s16x8 afrag = *(const s16x8*)&Wl[(nt * 16 + ql) * LP + kc * 32 + g * 8];
      acc[nt] = MFMA16(afrag, bfrag, acc[nt]);
    }
  }

  __syncthreads();                         // all MFMA LDS reads done; Xl reusable
  const int sl = w * 16 + ql;              // local s-row of this lane's column
  if (role < 2) {
    // stage [s][o] rows in LDS, then write coalesced 128B rows
#pragma unroll
    for (int nt = 0; nt < 4; ++nt) {
      const int ob = nt * 16 + g * 4;
      *(uint2*)&Xl[sl * LP + ob] = pack4((acc[nt][0] + bias[ob]) * oscl,
                                         (acc[nt][1] + bias[ob + 1]) * oscl,
                                         (acc[nt][2] + bias[ob + 2]) * oscl,
                                         (acc[nt][3] + bias[ob + 3]) * oscl);
    }
    __syncthreads();
    ushort* dst = (role == 0 ? qo : ko) + (size_t)bh * Sn * 64;
    const int ro = t >> 3, ch = t & 7;     // 8 threads per 128B row
#pragma unroll
    for (int p = 0; p < 2; ++p) {
      const int row = ro + p * 32;
      const uint4 v = *(const uint4*)&Xl[row * LP + ch * 8];
      *(uint4*)&dst[(size_t)(s0 + row) * 64 + ch * 8] = v;
    }
  } else {
    // transpose via LDS: [o][s] rows, coalesced 16B chunks
#pragma unroll
    for (int nt = 0; nt < 4; ++nt)
#pragma unroll
      for (int r = 0; r < 4; ++r) {
        const int o = nt * 16 + g * 4 + r;
        Xl[o * LP + sl] = f2bf(acc[nt][r] + bias[o]);
      }
    __syncthreads();
    const int ro = t >> 3, ch = t & 7;
#pragma unroll
    for (int p = 0; p < 2; ++p) {
      const int row = ro + p * 32;
      const uint4 v = *(const uint4*)&Xl[row * LP + ch * 8];
      *(uint4*)&vto[((size_t)bh * 64 + row) * Sn + s0 + ch * 8] = v;
    }
  }
}

// ---------------- Kernel 2: flash attention (R6/R11 verbatim — banked best, 49.2 us) ----------------
// block 512 = 8 waves; wave pair (w, w+4): 32-q col-tile wl=w&3, k-half h2=w>>2;
// max-free softmax; counted vmcnt(2); 2 barriers/step; ones-MFMA row-sum; LDS merge.
__global__ __launch_bounds__(512, 4) void flash_kernel(
    const ushort* __restrict__ q, const ushort* __restrict__ k,
    const ushort* __restrict__ vt, ushort* __restrict__ attn)
{
  __shared__ __align__(16) char smem[36864];      // K0|K1|V0|V1 (8KB each) / merge area
  float* mrg = (float*)smem;
  const int tid = threadIdx.x, lane = tid & 63, w = tid >> 6;
  const int m = lane & 31, hi = lane >> 5;
  const int wl = w & 3, h2 = w >> 2;              // col-tile, k-half
  const int hx  = hi ^ (m & 7);                   // K read chunk XOR
  const int hxv = hx ^ (h2 << 2);                 // V read chunk XOR (k-half folded)

  int lid = blockIdx.x + (blockIdx.y << 4);       // 0..511
  lid = (lid & 7) * 64 + (lid >> 3);              // bijective XCD swizzle
  const int bq = lid & 15, bh = lid >> 4;
  const int qrow = bq * 128 + wl * 32 + m;
  const int b = bh >> 3, h = bh & 7;

  const ushort* qp = q + ((size_t)bh * Sn + qrow) * 64 + hi * 8;
  const s16x8 qf0 = *(const s16x8*)(qp + 0);
  const s16x8 qf1 = *(const s16x8*)(qp + 16);
  const s16x8 qf2 = *(const s16x8*)(qp + 32);
  const s16x8 qf3 = *(const s16x8*)(qp + 48);

  const int srow = tid >> 3, sc = tid & 7, scs = sc ^ (srow & 7);
  const ushort* kS = k  + (size_t)bh * Sn * 64 + (size_t)srow * 64 + scs * 8;
  const ushort* vS = vt + ((size_t)bh * 64 + srow) * Sn + scs * 8;
  const uint dO = (uint)(tid * 16);
  char* KB0 = smem;          char* KB1 = smem + 8192;
  char* VB0 = smem + 16384;  char* VB1 = smem + 24576;

  const f32x16 z16 = {};
  f32x16 acc0 = {}, acc1 = {}, asum = {};
  union { ushort us[8]; s16x8 v; } onesU;
#pragma unroll
  for (int i = 0; i < 8; ++i) onesU.us[i] = 0x3F80;   // bf16 1.0
  const s16x8 ones = onesU.v;

  GLDS(kS, KB0 + dO); GLDS(vS, VB0 + dO);
  kS += 4096; vS += 64;

#define LDK(KB, S)     (*(const s16x8*)((KB)  + ((h2 * 32 + m) * 64 + (((2 * (S)) ^ hx ) << 3)) * 2))
#define LDV(VB, DT, S) (*(const s16x8*)((VB)  + (((DT) * 32 + m) * 64 + (((2 * (S)) ^ hxv) << 3)) * 2))

#define STEP(T, KB, VB, KBn, VBn) do {                                      \
    if ((T) < NT - 1) {                                                     \
      GLDS(kS, (KBn) + dO); GLDS(vS, (VBn) + dO);                           \
      kS += 4096; vS += 64;                                                 \
      asm volatile("s_waitcnt vmcnt(2)" ::: "memory");                      \
    } else {                                                                \
      asm volatile("s_waitcnt vmcnt(0)" ::: "memory");                      \
    }                                                                       \
    __builtin_amdgcn_s_barrier();                                           \
    __builtin_amdgcn_sched_barrier(0);                                      \
    f32x16 sta, stb;                                                        \
    __builtin_amdgcn_s_setprio(1);                                          \
    sta = MFMA32(LDK(KB, 0), qf0, z16);                                     \
    sta = MFMA32(LDK(KB, 1), qf1, sta);                                     \
    stb = MFMA32(LDK(KB, 2), qf2, z16);                                     \
    stb = MFMA32(LDK(KB, 3), qf3, stb);                                     \
    __builtin_amdgcn_s_setprio(0);                                          \
    f32x16 p;                                                               \
    _Pragma("unroll")                                                       \
    for (int i = 0; i < 16; ++i) p[i] = hexp2(sta[i] + stb[i]);             \
    uint uA, uB, uC, uD, uE, uF, uG, uH;                                    \
    uA = pkbf(p[0], p[1]);   uB = pkbf(p[4], p[5]);   SWAP32(uA, uB);       \
    uC = pkbf(p[2], p[3]);   uD = pkbf(p[6], p[7]);   SWAP32(uC, uD);       \
    uE = pkbf(p[8], p[9]);   uF = pkbf(p[12], p[13]); SWAP32(uE, uF);       \
    uG = pkbf(p[10], p[11]); uH = pkbf(p[14], p[15]); SWAP32(uG, uH);       \
    const s16x8 pb0 = mk8(uA, uC, uB, uD);                                  \
    const s16x8 pb1 = mk8(uE, uG, uF, uH);                                  \
    __builtin_amdgcn_s_setprio(1);                                          \
    acc0 = MFMA32(LDV(VB, 0, 0), pb0, acc0);                                \
    acc0 = MFMA32(LDV(VB, 0, 1), pb1, acc0);                                \
    acc1 = MFMA32(LDV(VB, 1, 0), pb0, acc1);                                \
    acc1 = MFMA32(LDV(VB, 1, 1), pb1, acc1);                                \
    asum = MFMA32(ones, pb0, asum);                                         \
    asum = MFMA32(ones, pb1, asum);                                         \
    __builtin_amdgcn_s_setprio(0);                                          \
    __builtin_amdgcn_s_barrier();                                           \
    __builtin_amdgcn_sched_barrier(0);                                      \
  } while (0)

  for (int T = 0; T < NT; T += 2) {
    STEP(T,     KB0, VB0, KB1, VB1);
    STEP(T + 1, KB1, VB1, KB0, VB0);
  }
#undef STEP
#undef LDK
#undef LDV

  const float lT = asum[0];                           // row-sum over this k-half
  float* mp = mrg + (size_t)(wl * 64 + lane) * 36;    // 144B stride, 16B aligned
  __syncthreads();                                    // drain LDS reads before overwrite
  if (h2) {
#pragma unroll
    for (int i = 0; i < 4; ++i) {
      f32x4 t0 = {acc0[4 * i], acc0[4 * i + 1], acc0[4 * i + 2], acc0[4 * i + 3]};
      f32x4 t1 = {acc1[4 * i], acc1[4 * i + 1], acc1[4 * i + 2], acc1[4 * i + 3]};
      *(f32x4*)(mp + 4 * i) = t0;
      *(f32x4*)(mp + 16 + 4 * i) = t1;
    }
    mp[32] = lT;
  }
  __syncthreads();
  if (!h2) {
    const float inv = 1.0f / (lT + mp[32]);
    ushort* ap = attn + ((size_t)(b * Sn + qrow)) * En + h * 64;
#pragma unroll
    for (int g2 = 0; g2 < 4; ++g2) {
      float a0 = (acc0[g2 * 4 + 0] + mp[g2 * 4 + 0]) * inv;
      float a1 = (acc0[g2 * 4 + 1] + mp[g2 * 4 + 1]) * inv;
      float a2 = (acc0[g2 * 4 + 2] + mp[g2 * 4 + 2]) * inv;
      float a3 = (acc0[g2 * 4 + 3] + mp[g2 * 4 + 3]) * inv;
      float c0 = (acc1[g2 * 4 + 0] + mp[16 + g2 * 4 + 0]) * inv;
      float c1 = (acc1[g2 * 4 + 1] + mp[16 + g2 * 4 + 1]) * inv;
      float c2 = (acc1[g2 * 4 + 2] + mp[16 + g2 * 4 + 2]) * inv;
      float c3 = (acc1[g2 * 4 + 3] + mp[16 + g2 * 4 + 3]) * inv;
      uint2 u0, u1;
      u0.x = pkbf(a0, a1); u0.y = pkbf(a2, a3);
      u1.x = pkbf(c0, c1); u1.y = pkbf(c2, c3);
      *(uint2*)&ap[g2 * 8 + hi * 4]      = u0;   // d = g2*8 + 4*hi + 0..3
      *(uint2*)&ap[32 + g2 * 8 + hi * 4] = u1;   // d = 32 + ...
    }
  }
}

// ---------------- Kernel 3: output projection, 128x128 tile, 8 waves (R9 verbatim) ----------------
__global__ __launch_bounds__(512) void outproj_kernel(
    const ushort* __restrict__ attn, const float* __restrict__ Wo,
    const float* __restrict__ bo, float* __restrict__ out)
{
  constexpr int LP = 72;
  __shared__ ushort Al[128 * LP];   // attn tile [m 128][e 64]
  __shared__ ushort Wl[128 * LP];   // Wo tile [n 128][e 64]
  const int t = threadIdx.x, lane = t & 63, w = t >> 6;
  const int g = lane >> 4, ml = lane & 15;
  const int wm = w >> 2, wn = w & 3;
  const int m0 = blockIdx.x * 128, n0 = blockIdx.y * 128;
  f32x4 acc[4][2];
#pragma unroll
  for (int i = 0; i < 4; ++i)
#pragma unroll
    for (int j = 0; j < 2; ++j) acc[i][j] = (f32x4){0.f, 0.f, 0.f, 0.f};

  const int srow = t >> 2, c0 = t & 3;     // 4 threads per row
  for (int e0 = 0; e0 < En; e0 += 64) {
    __syncthreads();
#pragma unroll
    for (int p = 0; p < 2; ++p) {          // attn: 8 chunks of 8 bf16 per row
      const int c = c0 + p * 4;
      const uint4 v = *(const uint4*)(attn + ((size_t)(m0 + srow)) * En + e0 + c * 8);
      *(uint4*)&Al[srow * LP + c * 8] = v;
    }
#pragma unroll
    for (int p = 0; p < 4; ++p) {          // Wo: 16 float4 per row, convert to bf16
      const int c = c0 + p * 4;
      const float4 v = *(const float4*)(Wo + ((size_t)(n0 + srow)) * En + e0 + c * 4);
      *(uint2*)&Wl[srow * LP + c * 4] = pack4(v.x, v.y, v.z, v.w);
    }
    __syncthreads();
#pragma unroll
    for (int kc = 0; kc < 2; ++kc) {
      s16x8 bfr[4];
#pragma unroll
      for (int mf = 0; mf < 4; ++mf)
        bfr[mf] = *(const s16x8*)&Al[(wm * 64 + mf * 16 + ml) * LP + kc * 32 + g * 8];
#pragma unroll
      for (int nf = 0; nf < 2; ++nf) {
        const s16x8 afr = *(const s16x8*)&Wl[(wn * 32 + nf * 16 + ml) * LP + kc * 32 + g * 8];
#pragma unroll
        for (int mf = 0; mf < 4; ++mf)
          acc[mf][nf] = MFMA16(afr, bfr[mf], acc[mf][nf]);
      }
    }
  }
#pragma unroll
  for (int mf = 0; mf < 4; ++mf) {
    const int mrow = m0 + wm * 64 + mf * 16 + ml;
#pragma unroll
    for (int nf = 0; nf < 2; ++nf) {
      const int ncol = n0 + wn * 32 + nf * 16 + g * 4;
      const float4 bias = *(const float4*)(bo + ncol);
      float4 o;
      o.x = acc[mf][nf][0] + bias.x;
      o.y = acc[mf][nf][1] + bias.y;
      o.z = acc[mf][nf][2] + bias.z;
      o.w = acc[mf][nf][3] + bias.w;
      *(float4*)&out[(size_t)mrow * En + ncol] = o;
    }
  }
}

extern "C" void kernel_launch(void* const* d_in, const int* in_sizes, int n_in,
                              void* d_out, int out_size, void* d_ws, size_t ws_size,
                              hipStream_t stream) {
  const float* Qi = (const float*)d_in[0];
  const float* Ki = (const float*)d_in[1];
  const float* Vi = (const float*)d_in[2];
  const float* Wq = (const float*)d_in[3];
  const float* bq = (const float*)d_in[4];
  const float* Wk = (const float*)d_in[5];
  const float* bk = (const float*)d_in[6];
  const float* Wv = (const float*)d_in[7];
  const float* bv = (const float*)d_in[8];
  const float* Wo = (const float*)d_in[9];
  const float* bo = (const float*)d_in[10];

  const size_t TEN = (size_t)BH * Sn * 64;   // 4 Mi elems per bf16 tensor
  ushort* qw  = (ushort*)d_ws;
  ushort* kw  = qw + TEN;
  ushort* vtw = kw + TEN;
  ushort* at  = vtw + TEN;                   // total 32 MB of ws

  proj_kernel<<<dim3(Sn / 64, BH, 3), 256, 0, stream>>>(
      Qi, Ki, Vi, Wq, bq, Wk, bk, Wv, bv, qw, kw, vtw);
  flash_kernel<<<dim3(16, 32), 512, 0, stream>>>(qw, kw, vtw, at);
  outproj_kernel<<<dim3(Bn * Sn / 128, En / 128), 512, 0, stream>>>(
      at, Wo, bo, (float*)d_out);
}

// Round 15
// 76.244 us; speedup vs baseline: 1.7401x; 1.0191x over previous
//
#include <hip/hip_runtime.h>

typedef float  f32x4  __attribute__((ext_vector_type(4)));
typedef float  f32x16 __attribute__((ext_vector_type(16)));
typedef short  s16x8  __attribute__((ext_vector_type(8)));

constexpr int Bn = 4, Sn = 2048, En = 512, Hn = 8;
constexpr int BH = Bn * Hn;   // 32
constexpr int NT = Sn / 64;   // 32 kv tiles
constexpr float QSCL = 0.125f * 1.44269504088896f;  // 1/sqrt(64) * log2(e), folded into q

static __device__ __forceinline__ ushort f2bf(float f) {
  union { float f; uint u; } v; v.f = f;
  uint r = v.u + 0x7fffu + ((v.u >> 16) & 1u);   // RNE
  return (ushort)(r >> 16);
}
static __device__ __forceinline__ float hexp2(float x) {
  float r; asm("v_exp_f32 %0, %1" : "=v"(r) : "v"(x)); return r;
}
static __device__ __forceinline__ uint pkbf(float lo, float hi2) {
  uint r; asm("v_cvt_pk_bf16_f32 %0, %1, %2" : "=v"(r) : "v"(lo), "v"(hi2)); return r;
}
static __device__ __forceinline__ uint2 pack4(float a, float b, float c, float d) {
  uint2 u; u.x = pkbf(a, b); u.y = pkbf(c, d); return u;   // 2 insts, RNE
}
#define SWAP32(a, b) asm("v_permlane32_swap_b32 %0, %1" : "+v"(a), "+v"(b))
static __device__ __forceinline__ s16x8 mk8(uint a, uint b, uint c, uint d) {
  union { uint u[4]; s16x8 v; } x; x.u[0] = a; x.u[1] = b; x.u[2] = c; x.u[3] = d; return x.v;
}
#define MFMA32(A, B, C) __builtin_amdgcn_mfma_f32_32x32x16_bf16((A), (B), (C), 0, 0, 0)
#define MFMA16(A, B, C) __builtin_amdgcn_mfma_f32_16x16x32_bf16((A), (B), (C), 0, 0, 0)
#define GLDS(SRC, DST) __builtin_amdgcn_global_load_lds( \
    (const __attribute__((address_space(1))) void*)(SRC), \
    (__attribute__((address_space(3))) void*)(DST), 16, 0, 0)

// ---------------- Kernel 1: per-head projections (R14 verbatim) ----------------
// role 0=q (pre-scaled), 1=k -> [BH,S,64]; role 2=v -> [BH,64,S].
// ALL outputs routed through LDS so global stores are coalesced 16B chunks.
__global__ __launch_bounds__(256) void proj_kernel(
    const float* __restrict__ Qi, const float* __restrict__ Ki, const float* __restrict__ Vi,
    const float* __restrict__ Wq, const float* __restrict__ bq,
    const float* __restrict__ Wk, const float* __restrict__ bk,
    const float* __restrict__ Wv, const float* __restrict__ bv,
    ushort* __restrict__ qo, ushort* __restrict__ ko, ushort* __restrict__ vto)
{
  constexpr int LP = 72;
  __shared__ ushort Xl[64 * LP];
  __shared__ ushort Wl[64 * LP];
  const int role = blockIdx.z;
  const float* X    = role == 0 ? Qi : (role == 1 ? Ki : Vi);
  const float* W    = role == 0 ? Wq : (role == 1 ? Wk : Wv);
  const float* bias = role == 0 ? bq : (role == 1 ? bk : bv);
  const float oscl  = role == 0 ? QSCL : 1.0f;
  const int t = threadIdx.x, lane = t & 63, w = t >> 6;
  const int g = lane >> 4, ql = lane & 15;
  const int bh = blockIdx.y, b = bh >> 3, h = bh & 7;
  const int s0 = blockIdx.x * 64;

  {
    const int row = t >> 4, c = t & 15;
#pragma unroll
    for (int p = 0; p < 4; ++p) {
      const int rr = row + p * 16;
      const float4 wv = *(const float4*)(W + rr * 64 + c * 4);
      *(uint2*)&Wl[rr * LP + c * 4] = pack4(wv.x, wv.y, wv.z, wv.w);
      const float4 xv = *(const float4*)(X + ((size_t)b * Sn + s0 + rr) * En + h * 64 + c * 4);
      *(uint2*)&Xl[rr * LP + c * 4] = pack4(xv.x, xv.y, xv.z, xv.w);
    }
  }
  __syncthreads();

  f32x4 acc[4];
#pragma unroll
  for (int i = 0; i < 4; ++i) acc[i] = (f32x4){0.f, 0.f, 0.f, 0.f};
#pragma unroll
  for (int kc = 0; kc < 2; ++kc) {
    const s16x8 bfrag = *(const s16x8*)&Xl[(w * 16 + ql) * LP + kc * 32 + g * 8];
#pragma unroll
    for (int nt = 0; nt < 4; ++nt) {
      const s16x8 afrag = *(const s16x8*)&Wl[(nt * 16 + ql) * LP + kc * 32 + g * 8];
      acc[nt] = MFMA16(afrag, bfrag, acc[nt]);
    }
  }

  __syncthreads();                         // all MFMA LDS reads done; Xl reusable
  const int sl = w * 16 + ql;              // local s-row of this lane's column
  if (role < 2) {
#pragma unroll
    for (int nt = 0; nt < 4; ++nt) {
      const int ob = nt * 16 + g * 4;
      *(uint2*)&Xl[sl * LP + ob] = pack4((acc[nt][0] + bias[ob]) * oscl,
                                         (acc[nt][1] + bias[ob + 1]) * oscl,
                                         (acc[nt][2] + bias[ob + 2]) * oscl,
                                         (acc[nt][3] + bias[ob + 3]) * oscl);
    }
    __syncthreads();
    ushort* dst = (role == 0 ? qo : ko) + (size_t)bh * Sn * 64;
    const int ro = t >> 3, ch = t & 7;     // 8 threads per 128B row
#pragma unroll
    for (int p = 0; p < 2; ++p) {
      const int row = ro + p * 32;
      const uint4 v = *(const uint4*)&Xl[row * LP + ch * 8];
      *(uint4*)&dst[(size_t)(s0 + row) * 64 + ch * 8] = v;
    }
  } else {
#pragma unroll
    for (int nt = 0; nt < 4; ++nt)
#pragma unroll
      for (int r = 0; r < 4; ++r) {
        const int o = nt * 16 + g * 4 + r;
        Xl[o * LP + sl] = f2bf(acc[nt][r] + bias[o]);
      }
    __syncthreads();
    const int ro = t >> 3, ch = t & 7;
#pragma unroll
    for (int p = 0; p < 2; ++p) {
      const int row = ro + p * 32;
      const uint4 v = *(const uint4*)&Xl[row * LP + ch * 8];
      *(uint4*)&vto[((size_t)bh * 64 + row) * Sn + s0 + ch * 8] = v;
    }
  }
}

// ---------------- Kernel 2: flash attention (R6/R11 verbatim — banked best, 49.0 us) ----------------
__global__ __launch_bounds__(512, 4) void flash_kernel(
    const ushort* __restrict__ q, const ushort* __restrict__ k,
    const ushort* __restrict__ vt, ushort* __restrict__ attn)
{
  __shared__ __align__(16) char smem[36864];      // K0|K1|V0|V1 (8KB each) / merge area
  float* mrg = (float*)smem;
  const int tid = threadIdx.x, lane = tid & 63, w = tid >> 6;
  const int m = lane & 31, hi = lane >> 5;
  const int wl = w & 3, h2 = w >> 2;              // col-tile, k-half
  const int hx  = hi ^ (m & 7);                   // K read chunk XOR
  const int hxv = hx ^ (h2 << 2);                 // V read chunk XOR (k-half folded)

  int lid = blockIdx.x + (blockIdx.y << 4);       // 0..511
  lid = (lid & 7) * 64 + (lid >> 3);              // bijective XCD swizzle
  const int bq = lid & 15, bh = lid >> 4;
  const int qrow = bq * 128 + wl * 32 + m;
  const int b = bh >> 3, h = bh & 7;

  const ushort* qp = q + ((size_t)bh * Sn + qrow) * 64 + hi * 8;
  const s16x8 qf0 = *(const s16x8*)(qp + 0);
  const s16x8 qf1 = *(const s16x8*)(qp + 16);
  const s16x8 qf2 = *(const s16x8*)(qp + 32);
  const s16x8 qf3 = *(const s16x8*)(qp + 48);

  const int srow = tid >> 3, sc = tid & 7, scs = sc ^ (srow & 7);
  const ushort* kS = k  + (size_t)bh * Sn * 64 + (size_t)srow * 64 + scs * 8;
  const ushort* vS = vt + ((size_t)bh * 64 + srow) * Sn + scs * 8;
  const uint dO = (uint)(tid * 16);
  char* KB0 = smem;          char* KB1 = smem + 8192;
  char* VB0 = smem + 16384;  char* VB1 = smem + 24576;

  const f32x16 z16 = {};
  f32x16 acc0 = {}, acc1 = {}, asum = {};
  union { ushort us[8]; s16x8 v; } onesU;
#pragma unroll
  for (int i = 0; i < 8; ++i) onesU.us[i] = 0x3F80;   // bf16 1.0
  const s16x8 ones = onesU.v;

  GLDS(kS, KB0 + dO); GLDS(vS, VB0 + dO);
  kS += 4096; vS += 64;

#define LDK(KB, S)     (*(const s16x8*)((KB)  + ((h2 * 32 + m) * 64 + (((2 * (S)) ^ hx ) << 3)) * 2))
#define LDV(VB, DT, S) (*(const s16x8*)((VB)  + (((DT) * 32 + m) * 64 + (((2 * (S)) ^ hxv) << 3)) * 2))

#define STEP(T, KB, VB, KBn, VBn) do {                                      \
    if ((T) < NT - 1) {                                                     \
      GLDS(kS, (KBn) + dO); GLDS(vS, (VBn) + dO);                           \
      kS += 4096; vS += 64;                                                 \
      asm volatile("s_waitcnt vmcnt(2)" ::: "memory");                      \
    } else {                                                                \
      asm volatile("s_waitcnt vmcnt(0)" ::: "memory");                      \
    }                                                                       \
    __builtin_amdgcn_s_barrier();                                           \
    __builtin_amdgcn_sched_barrier(0);                                      \
    f32x16 sta, stb;                                                        \
    __builtin_amdgcn_s_setprio(1);                                          \
    sta = MFMA32(LDK(KB, 0), qf0, z16);                                     \
    sta = MFMA32(LDK(KB, 1), qf1, sta);                                     \
    stb = MFMA32(LDK(KB, 2), qf2, z16);                                     \
    stb = MFMA32(LDK(KB, 3), qf3, stb);                                     \
    __builtin_amdgcn_s_setprio(0);                                          \
    f32x16 p;                                                               \
    _Pragma("unroll")                                                       \
    for (int i = 0; i < 16; ++i) p[i] = hexp2(sta[i] + stb[i]);             \
    uint uA, uB, uC, uD, uE, uF, uG, uH;                                    \
    uA = pkbf(p[0], p[1]);   uB = pkbf(p[4], p[5]);   SWAP32(uA, uB);       \
    uC = pkbf(p[2], p[3]);   uD = pkbf(p[6], p[7]);   SWAP32(uC, uD);       \
    uE = pkbf(p[8], p[9]);   uF = pkbf(p[12], p[13]); SWAP32(uE, uF);       \
    uG = pkbf(p[10], p[11]); uH = pkbf(p[14], p[15]); SWAP32(uG, uH);       \
    const s16x8 pb0 = mk8(uA, uC, uB, uD);                                  \
    const s16x8 pb1 = mk8(uE, uG, uF, uH);                                  \
    __builtin_amdgcn_s_setprio(1);                                          \
    acc0 = MFMA32(LDV(VB, 0, 0), pb0, acc0);                                \
    acc0 = MFMA32(LDV(VB, 0, 1), pb1, acc0);                                \
    acc1 = MFMA32(LDV(VB, 1, 0), pb0, acc1);                                \
    acc1 = MFMA32(LDV(VB, 1, 1), pb1, acc1);                                \
    asum = MFMA32(ones, pb0, asum);                                         \
    asum = MFMA32(ones, pb1, asum);                                         \
    __builtin_amdgcn_s_setprio(0);                                          \
    __builtin_amdgcn_s_barrier();                                           \
    __builtin_amdgcn_sched_barrier(0);                                      \
  } while (0)

  for (int T = 0; T < NT; T += 2) {
    STEP(T,     KB0, VB0, KB1, VB1);
    STEP(T + 1, KB1, VB1, KB0, VB0);
  }
#undef STEP
#undef LDK
#undef LDV

  const float lT = asum[0];                           // row-sum over this k-half
  float* mp = mrg + (size_t)(wl * 64 + lane) * 36;    // 144B stride, 16B aligned
  __syncthreads();                                    // drain LDS reads before overwrite
  if (h2) {
#pragma unroll
    for (int i = 0; i < 4; ++i) {
      f32x4 t0 = {acc0[4 * i], acc0[4 * i + 1], acc0[4 * i + 2], acc0[4 * i + 3]};
      f32x4 t1 = {acc1[4 * i], acc1[4 * i + 1], acc1[4 * i + 2], acc1[4 * i + 3]};
      *(f32x4*)(mp + 4 * i) = t0;
      *(f32x4*)(mp + 16 + 4 * i) = t1;
    }
    mp[32] = lT;
  }
  __syncthreads();
  if (!h2) {
    const float inv = 1.0f / (lT + mp[32]);
    ushort* ap = attn + ((size_t)(b * Sn + qrow)) * En + h * 64;
#pragma unroll
    for (int g2 = 0; g2 < 4; ++g2) {
      float a0 = (acc0[g2 * 4 + 0] + mp[g2 * 4 + 0]) * inv;
      float a1 = (acc0[g2 * 4 + 1] + mp[g2 * 4 + 1]) * inv;
      float a2 = (acc0[g2 * 4 + 2] + mp[g2 * 4 + 2]) * inv;
      float a3 = (acc0[g2 * 4 + 3] + mp[g2 * 4 + 3]) * inv;
      float c0 = (acc1[g2 * 4 + 0] + mp[16 + g2 * 4 + 0]) * inv;
      float c1 = (acc1[g2 * 4 + 1] + mp[16 + g2 * 4 + 1]) * inv;
      float c2 = (acc1[g2 * 4 + 2] + mp[16 + g2 * 4 + 2]) * inv;
      float c3 = (acc1[g2 * 4 + 3] + mp[16 + g2 * 4 + 3]) * inv;
      uint2 u0, u1;
      u0.x = pkbf(a0, a1); u0.y = pkbf(a2, a3);
      u1.x = pkbf(c0, c1); u1.y = pkbf(c2, c3);
      *(uint2*)&ap[g2 * 8 + hi * 4]      = u0;   // d = g2*8 + 4*hi + 0..3
      *(uint2*)&ap[32 + g2 * 8 + hi * 4] = u1;   // d = 32 + ...
    }
  }
}

// ---------------- Kernel 3: output projection, 128x64 tile, 2 blocks/CU ----------------
// out[m][n] = sum_e attn[m][e]*Wo[n][e] + bo[n]. grid (64, 8) = 512 blocks, 512 thr.
// Wave w: m-quarter wm=w&3 (32 rows), n-half wn=w>>2 (32 cols); acc[2][2] 16x16 frags.
// LDS 27.6KB -> two blocks co-resident per CU (latency hiding across barrier stalls).
__global__ __launch_bounds__(512) void outproj_kernel(
    const ushort* __restrict__ attn, const float* __restrict__ Wo,
    const float* __restrict__ bo, float* __restrict__ out)
{
  constexpr int LP = 72;
  __shared__ ushort Al[128 * LP];   // attn tile [m 128][e 64]
  __shared__ ushort Wl[64 * LP];    // Wo tile [n 64][e 64]
  const int t = threadIdx.x, lane = t & 63, w = t >> 6;
  const int g = lane >> 4, ml = lane & 15;
  const int wm = w & 3, wn = w >> 2;
  const int m0 = blockIdx.x * 128, n0 = blockIdx.y * 64;
  f32x4 acc[2][2];
#pragma unroll
  for (int i = 0; i < 2; ++i)
#pragma unroll
    for (int j = 0; j < 2; ++j) acc[i][j] = (f32x4){0.f, 0.f, 0.f, 0.f};

  const int arow = t >> 2, ac0 = t & 3;    // attn: 4 threads/row, 2 x 16B chunks
  const int wrow = t >> 3, wc0 = t & 7;    // Wo: 8 threads/row, 2 x float4
  for (int e0 = 0; e0 < En; e0 += 64) {
    __syncthreads();
#pragma unroll
    for (int p = 0; p < 2; ++p) {
      const int c = ac0 + p * 4;
      const uint4 v = *(const uint4*)(attn + ((size_t)(m0 + arow)) * En + e0 + c * 8);
      *(uint4*)&Al[arow * LP + c * 8] = v;
    }
#pragma unroll
    for (int p = 0; p < 2; ++p) {
      const int c = wc0 + p * 8;
      const float4 v = *(const float4*)(Wo + ((size_t)(n0 + wrow)) * En + e0 + c * 4);
      *(uint2*)&Wl[wrow * LP + c * 4] = pack4(v.x, v.y, v.z, v.w);
    }
    __syncthreads();
#pragma unroll
    for (int kc = 0; kc < 2; ++kc) {
      s16x8 bfr[2];
#pragma unroll
      for (int mf = 0; mf < 2; ++mf)
        bfr[mf] = *(const s16x8*)&Al[(wm * 32 + mf * 16 + ml) * LP + kc * 32 + g * 8];
#pragma unroll
      for (int nf = 0; nf < 2; ++nf) {
        const s16x8 afr = *(const s16x8*)&Wl[(wn * 32 + nf * 16 + ml) * LP + kc * 32 + g * 8];
#pragma unroll
        for (int mf = 0; mf < 2; ++mf)
          acc[mf][nf] = MFMA16(afr, bfr[mf], acc[mf][nf]);
      }
    }
  }
#pragma unroll
  for (int mf = 0; mf < 2; ++mf) {
    const int mrow = m0 + wm * 32 + mf * 16 + ml;
#pragma unroll
    for (int nf = 0; nf < 2; ++nf) {
      const int ncol = n0 + wn * 32 + nf * 16 + g * 4;
      const float4 bias = *(const float4*)(bo + ncol);
      float4 o;
      o.x = acc[mf][nf][0] + bias.x;
      o.y = acc[mf][nf][1] + bias.y;
      o.z = acc[mf][nf][2] + bias.z;
      o.w = acc[mf][nf][3] + bias.w;
      *(float4*)&out[(size_t)mrow * En + ncol] = o;
    }
  }
}

extern "C" void kernel_launch(void* const* d_in, const int* in_sizes, int n_in,
                              void* d_out, int out_size, void* d_ws, size_t ws_size,
                              hipStream_t stream) {
  const float* Qi = (const float*)d_in[0];
  const float* Ki = (const float*)d_in[1];
  const float* Vi = (const float*)d_in[2];
  const float* Wq = (const float*)d_in[3];
  const float* bq = (const float*)d_in[4];
  const float* Wk = (const float*)d_in[5];
  const float* bk = (const float*)d_in[6];
  const float* Wv = (const float*)d_in[7];
  const float* bv = (const float*)d_in[8];
  const float* Wo = (const float*)d_in[9];
  const float* bo = (const float*)d_in[10];

  const size_t TEN = (size_t)BH * Sn * 64;   // 4 Mi elems per bf16 tensor
  ushort* qw  = (ushort*)d_ws;
  ushort* kw  = qw + TEN;
  ushort* vtw = kw + TEN;
  ushort* at  = vtw + TEN;                   // total 32 MB of ws

  proj_kernel<<<dim3(Sn / 64, BH, 3), 256, 0, stream>>>(
      Qi, Ki, Vi, Wq, bq, Wk, bk, Wv, bv, qw, kw, vtw);
  flash_kernel<<<dim3(16, 32), 512, 0, stream>>>(qw, kw, vtw, at);
  outproj_kernel<<<dim3(Bn * Sn / 128, En / 64), 512, 0, stream>>>(
      at, Wo, bo, (float*)d_out);
}